// Round 1
// baseline (210.625 us; speedup 1.0000x reference)
//
#include <hip/hip_runtime.h>
#include <hip/hip_bf16.h>

#define B_   8
#define C_   128
#define HW_  16384
#define N_   16
#define EPS_ 1e-7f

typedef unsigned short u16;
typedef __attribute__((ext_vector_type(8))) short s8v;
typedef __attribute__((ext_vector_type(4))) short s4v;
typedef __attribute__((ext_vector_type(4))) float f4v;

__device__ __forceinline__ u16 f2b(float f) {
  union { __hip_bfloat16 b; u16 u; } cv; cv.b = __float2bfloat16(f); return cv.u;
}
__device__ __forceinline__ float b2f(u16 u) {
  union { float f; unsigned int i; } cv; cv.i = ((unsigned int)u) << 16; return cv.f;
}
__device__ __forceinline__ float wredsum(float v) {
#pragma unroll
  for (int o = 32; o > 0; o >>= 1) v += __shfl_xor(v, o, 64);
  return v;
}
__device__ __forceinline__ float wredmax(float v) {
#pragma unroll
  for (int o = 32; o > 0; o >>= 1) v = fmaxf(v, __shfl_xor(v, o, 64));
  return v;
}

// ---------------- Kernel 1: per-batch partial Gram + fused misc -------------
// 512 threads (8 waves), grid (65, 8), LB(512,4) -> 2 blocks/CU = 16 waves/CU.
// Round-5 restructure: ONE 256-px LDS tile (128x256 bf16 = exactly 64 KB,
// XOR-swizzled byte^=(row&7)<<4 so frag reads are at the bank floor) ->
// 1 barrier per block instead of 4, and all 16 float4 loads issued up front
// (2x MLP). sx computed from fp32 registers via half-wave shuffle reduce on
// ALL threads (old version had tid<128 re-walk the LDS tile: ~770 serial VALU
// ops on 1/4 of threads while 6 waves waited at the barrier).
#define XSB 512  // LDS row stride in BYTES (256 u16, no pad; swizzle instead)
__global__ __launch_bounds__(512, 4) void k_gram(
    const float* __restrict__ x, float* __restrict__ pbuf, float* __restrict__ psx,
    const float* __restrict__ Wsa, const float* __restrict__ kn,
    const float* __restrict__ Wo, float* __restrict__ u,
    float* __restrict__ loss_out, u16* __restrict__ wo_bf) {
  __shared__ u16 Xb[C_ * 256];   // 65536 B
  const int tid = threadIdx.x;
  const int b = blockIdx.y;

  if (blockIdx.x == 64) {  // ---- misc blocks ----
    if (b == 0) {          // u[r] = column sums of Wsa
      if (tid < C_) {
        float s = 0.f;
        for (int i = 0; i < C_; ++i) s += Wsa[i * C_ + tid];
        u[tid] = s;
      }
    } else if (b == 1) {   // orth loss (first 256 threads compute)
      float* smf = (float*)Xb;          // [0..15]=nrm, [16..23]=per-wave partials
      const int i = tid >> 4, j = tid & 15;
      float s = 0.f;
      if (tid < 256) {
        for (int c = 0; c < C_; ++c) s += kn[i * C_ + c] * kn[j * C_ + c];
        if (i == j) smf[i] = sqrtf(s);
      }
      __syncthreads();
      float l2 = 0.f;
      if (tid < 256) {
        float l = s / (smf[i] * smf[j] + EPS_) - (i == j ? 1.f : 0.f);
        l2 = l * l;
      }
      float wv = wredsum(l2);
      if ((tid & 63) == 0) smf[16 + (tid >> 6)] = wv;
      __syncthreads();
      if (tid == 0) {
        float t = 0.f;
        for (int k = 0; k < 8; ++k) t += smf[16 + k];
        loss_out[0] = 0.1f * logf(t + 1.f);
      }
    } else if (b == 2) {   // Wo -> bf16
#pragma unroll
      for (int j = 0; j < 8; ++j) {
        int f = tid + 512 * j;
        float4 v = ((const float4*)Wo)[f];
        s4v s; s[0] = (short)f2b(v.x); s[1] = (short)f2b(v.y);
        s[2] = (short)f2b(v.z); s[3] = (short)f2b(v.w);
        ((s4v*)wo_bf)[f] = s;
      }
    }
    return;
  }

  const int p0 = blockIdx.x * 256;
  const int lane = tid & 63;
  const int w = tid >> 6;                 // wave 0..7
  const int m = lane & 15, q = lane >> 4;
  const int rb = (w & 3) * 32, cb = (w >> 2) * 64;

  const float* xb = x + (size_t)b * C_ * HW_;
  const int l32 = tid & 31;
  const int rbase = tid >> 5;             // 0..15
  const float* ro = xb + (size_t)rbase * HW_ + p0 + 4 * l32;
  char* lds = (char*)Xb;

  // issue all 16 loads up front (deep MLP)
  float4 v[8], v2[8];
#pragma unroll
  for (int j = 0; j < 8; ++j) v[j]  = *(const float4*)(ro + (size_t)(16 * j) * HW_);
#pragma unroll
  for (int j = 0; j < 8; ++j) v2[j] = *(const float4*)(ro + (size_t)(16 * j) * HW_ + 128);

  const int swc = (rbase & 7) << 4;       // row&7 const per thread (rows rbase+16j)
  float rs[8];
#pragma unroll
  for (int j = 0; j < 8; ++j) {
    const int c = rbase + 16 * j;
    s4v s; s[0] = (short)f2b(v[j].x); s[1] = (short)f2b(v[j].y);
    s[2] = (short)f2b(v[j].z); s[3] = (short)f2b(v[j].w);
    *(s4v*)(lds + c * XSB + ((8 * l32) ^ swc)) = s;
    rs[j] = v[j].x + v[j].y + v[j].z + v[j].w;
  }
#pragma unroll
  for (int j = 0; j < 8; ++j) {
    const int c = rbase + 16 * j;
    s4v s; s[0] = (short)f2b(v2[j].x); s[1] = (short)f2b(v2[j].y);
    s[2] = (short)f2b(v2[j].z); s[3] = (short)f2b(v2[j].w);
    *(s4v*)(lds + c * XSB + ((256 + 8 * l32) ^ swc)) = s;
    rs[j] += v2[j].x + v2[j].y + v2[j].z + v2[j].w;
  }
  // half-wave (32-lane) reduce: row rbase+16j is owned by lanes sharing tid>>5
#pragma unroll
  for (int o = 16; o > 0; o >>= 1)
#pragma unroll
    for (int j = 0; j < 8; ++j) rs[j] += __shfl_xor(rs[j], o, 64);
  if (l32 == 0) {
#pragma unroll
    for (int j = 0; j < 8; ++j)
      psx[(blockIdx.x * B_ + b) * C_ + rbase + 16 * j] = rs[j];
  }
  __syncthreads();   // the ONLY barrier

  f4v acc[2][4];
#pragma unroll
  for (int a = 0; a < 2; ++a)
#pragma unroll
    for (int c2 = 0; c2 < 4; ++c2) acc[a][c2] = (f4v){0.f, 0.f, 0.f, 0.f};

  const int swf = (m & 7) << 4;           // frag rows rb/cb are mults of 32
#pragma unroll
  for (int s = 0; s < 8; ++s) {
    const int off = (64 * s + 16 * q) ^ swf;
    s8v Af[2], Bf[4];
#pragma unroll
    for (int a = 0; a < 2; ++a)
      Af[a] = *(const s8v*)(lds + (rb + 16 * a + m) * XSB + off);
#pragma unroll
    for (int c2 = 0; c2 < 4; ++c2)
      Bf[c2] = *(const s8v*)(lds + (cb + 16 * c2 + m) * XSB + off);
#pragma unroll
    for (int a = 0; a < 2; ++a)
#pragma unroll
      for (int c2 = 0; c2 < 4; ++c2)
        acc[a][c2] = __builtin_amdgcn_mfma_f32_16x16x32_bf16(Af[a], Bf[c2], acc[a][c2], 0, 0, 0);
  }

  float* pg = pbuf + ((size_t)(blockIdx.x * B_ + b) << 14);
#pragma unroll
  for (int a = 0; a < 2; ++a)
#pragma unroll
    for (int c2 = 0; c2 < 4; ++c2)
#pragma unroll
      for (int r = 0; r < 4; ++r) {
        int row = rb + 16 * a + 4 * q + r;  // C/D: row=(lane>>4)*4+reg
        int col = cb + 16 * c2 + m;         //      col=lane&15
        pg[row * C_ + col] = acc[a][c2][r];
      }
}

// ---------------- reduce 64 partials -> G, sx (float4) ----------------------
// Round-5: 264 blocks x 128 threads (was 132 x 256) -> all 256 CUs active
// instead of half, same total wave count.
__global__ __launch_bounds__(128) void k_greduce(const float4* __restrict__ pbuf4,
                                                 const float* __restrict__ psx,
                                                 float4* __restrict__ G4,
                                                 float* __restrict__ sx) {
  const int blk = blockIdx.x;
  if (blk < 256) {
    const int gid = blk * 128 + threadIdx.x;  // [0, 32768)
    const int b = gid >> 12, idx4 = gid & 4095;
    float4 s = {0.f, 0.f, 0.f, 0.f};
#pragma unroll 16
    for (int ch = 0; ch < 64; ++ch) {
      float4 p = pbuf4[((size_t)(ch * B_ + b) << 12) + idx4];
      s.x += p.x; s.y += p.y; s.z += p.z; s.w += p.w;
    }
    G4[gid] = s;
  } else {
    const int tt = (blk - 256) * 128 + threadIdx.x;  // [0, 1024)
    const int b = tt >> 7, c = tt & 127;
    float s = 0.f;
#pragma unroll 16
    for (int ch = 0; ch < 64; ++ch) s += psx[(ch * B_ + b) * C_ + c];
    sx[tt] = s;
  }
}

// ---------------- Kernel 2: per-(batch, column) G-derived quantities --------
__global__ __launch_bounds__(64) void k_cols(
    const float* __restrict__ G, const float* __restrict__ sx,
    const float* __restrict__ Wr, const float* __restrict__ Wsa,
    const float* __restrict__ Wo, const float* __restrict__ kn,
    const float* __restrict__ u,
    float* diagR, float* diagSA, float* colsumSA, float* diagO,
    float* prv, float* psav, float* pov, float* rel, float* diagN, float* ksx) {
  const int b = blockIdx.y;
  const int col = blockIdx.x;
  const int lane = threadIdx.x;
  const float* Gb = G + b * C_ * C_;
  const float4* g0 = (const float4*)(Gb + lane * C_);
  const float4* g1 = (const float4*)(Gb + (64 + lane) * C_);
  const float sx0 = sx[b * C_ + lane], sx1 = sx[b * C_ + 64 + lane];

  if (col < C_) {
    const float4* wr = (const float4*)(Wr + col * C_);
    const float4* wa = (const float4*)(Wsa + col * C_);
    const float4* wo = (const float4*)(Wo + col * C_);
    float t0r = 0, t1r = 0, t0a = 0, t1a = 0, t0o = 0, t1o = 0;
    for (int c = 0; c < 32; ++c) {
      float4 a0 = g0[c], a1 = g1[c];
      float4 vr = wr[c], va = wa[c], vo = wo[c];
      t0r += a0.x * vr.x + a0.y * vr.y + a0.z * vr.z + a0.w * vr.w;
      t1r += a1.x * vr.x + a1.y * vr.y + a1.z * vr.z + a1.w * vr.w;
      t0a += a0.x * va.x + a0.y * va.y + a0.z * va.z + a0.w * va.w;
      t1a += a1.x * va.x + a1.y * va.y + a1.z * va.z + a1.w * va.w;
      t0o += a0.x * vo.x + a0.y * vo.y + a0.z * vo.z + a0.w * vo.w;
      t1o += a1.x * vo.x + a1.y * vo.y + a1.z * vo.z + a1.w * vo.w;
    }
    float wr0 = Wr[col * C_ + lane], wr1 = Wr[col * C_ + 64 + lane];
    float wa0 = Wsa[col * C_ + lane], wa1 = Wsa[col * C_ + 64 + lane];
    float wo0 = Wo[col * C_ + lane], wo1 = Wo[col * C_ + 64 + lane];
    float u0 = u[lane], u1 = u[64 + lane];
    float dR = wredsum(wr0 * t0r + wr1 * t1r);
    float pR = wredsum(wr0 * sx0 + wr1 * sx1);
    float dA = wredsum(wa0 * t0a + wa1 * t1a);
    float cA = wredsum(u0 * t0a + u1 * t1a);
    float pA = wredsum(wa0 * sx0 + wa1 * sx1);
    float dO = wredsum(wo0 * t0o + wo1 * t1o);
    float pO = wredsum(wo0 * sx0 + wo1 * sx1);
    float rl[N_];
#pragma unroll
    for (int n = 0; n < N_; ++n)
      rl[n] = wredsum(kn[n * C_ + lane] * t0r + kn[n * C_ + 64 + lane] * t1r);
    if (lane == 0) {
      diagR[b * C_ + col] = dR;  prv[b * C_ + col] = pR;
      diagSA[b * C_ + col] = dA; colsumSA[b * C_ + col] = cA; psav[b * C_ + col] = pA;
      diagO[b * C_ + col] = dO;  pov[b * C_ + col] = pO;
      for (int n = 0; n < N_; ++n) rel[(b * N_ + n) * C_ + col] = rl[n];
    }
  } else {
    const int n = col - C_;
    const float4* wk = (const float4*)(kn + n * C_);
    float t0 = 0, t1 = 0;
    for (int c = 0; c < 32; ++c) {
      float4 a0 = g0[c], a1 = g1[c], vk = wk[c];
      t0 += a0.x * vk.x + a0.y * vk.y + a0.z * vk.z + a0.w * vk.w;
      t1 += a1.x * vk.x + a1.y * vk.y + a1.z * vk.z + a1.w * vk.w;
    }
    float k0v = kn[n * C_ + lane], k1v = kn[n * C_ + 64 + lane];
    float dN = wredsum(k0v * t0 + k1v * t1);
    float kx = wredsum(k0v * sx0 + k1v * sx1);
    if (lane == 0) { diagN[b * N_ + n] = dN; ksx[b * N_ + n] = kx; }
  }
}

// ---------------- Kernel 3: per-batch assembly -> A[b,c], B[b,c] ------------
// Round-5: att stored transposed [c][n] (conflict-free both directions) and
// the (n)-reductions run on all 128 threads (8 lanes per n, 16 iters + 3
// shuffles) instead of 16 threads x 128 serial iters.
__global__ __launch_bounds__(128) void k_asm(
    const float* diagR, const float* diagSA, const float* colsumSA, const float* diagO,
    const float* prv, const float* psav, const float* pov,
    const float* rel, const float* diagN, const float* ksx,
    const float* br, const float* bo, const float* bsa, const float* alpha,
    float* Aout, float* Bout) {
  const int b = blockIdx.x;
  const int t = threadIdx.x;
  __shared__ float rb2[2];
  __shared__ float att_s[C_][N_ + 1];
  __shared__ float s1_s[C_], s2_s[C_];
  __shared__ float inv_s[N_], fmi_s[N_];
  const float hw = (float)HW_;
  const float bsa_c = bsa[t], br_c = br[t], bo_c = bo[t];
  const float psa_c = psav[b * C_ + t], pr_c = prv[b * C_ + t], po_c = pov[b * C_ + t];

  float bsum, psum, mx, ssum;
  { float wv = wredsum(bsa_c); if ((t & 63) == 0) rb2[t >> 6] = wv; __syncthreads();
    bsum = rb2[0] + rb2[1]; __syncthreads(); }
  { float wv = wredsum(psa_c); if ((t & 63) == 0) rb2[t >> 6] = wv; __syncthreads();
    psum = rb2[0] + rb2[1]; __syncthreads(); }

  const float nxr = sqrtf(fmaxf(diagR[b * C_ + t] + 2.f * br_c * pr_c + hw * br_c * br_c, 0.f));
  s1_s[t] = po_c + hw * bo_c;
  s2_s[t] = diagO[b * C_ + t] + 2.f * bo_c * po_c + hw * bo_c * bo_c;
  const float colsum = colsumSA[b * C_ + t] + bsum * psa_c + bsa_c * (psum + hw * bsum);
  const float diagv = diagSA[b * C_ + t] + 2.f * bsa_c * psa_c + hw * bsa_c * bsa_c;
  const float fm = (colsum - diagv) * (1.f / (float)C_);

  { float wv = wredmax(fm); if ((t & 63) == 0) rb2[t >> 6] = wv; __syncthreads();
    mx = fmaxf(rb2[0], rb2[1]); __syncthreads(); }
  const float ee = expf(fm - mx);
  { float wv = wredsum(ee); if ((t & 63) == 0) rb2[t >> 6] = wv; __syncthreads();
    ssum = rb2[0] + rb2[1]; __syncthreads(); }
  const float reg = ee / ssum;

  float r[N_];
  float rmax = -1e30f;
#pragma unroll
  for (int n = 0; n < N_; ++n) {
    float al = fminf(fmaxf(alpha[n], 0.f), 1.f);
    float nxn = sqrtf(fmaxf(diagN[b * N_ + n], 0.f));
    float rv = (rel[(b * N_ + n) * C_ + t] + br_c * ksx[b * N_ + n]) / (nxn * nxr + EPS_) + al * reg;
    r[n] = rv; rmax = fmaxf(rmax, rv);
  }
  float es = 0.f;
#pragma unroll
  for (int n = 0; n < N_; ++n) { r[n] = expf(r[n] - rmax); es += r[n]; }
  const float ies = 1.f / es;
#pragma unroll
  for (int n = 0; n < N_; ++n) att_s[t][n] = r[n] * ies;
  __syncthreads();

  {
    const int nn = t >> 3, g = t & 7;     // 8 lanes per class n
    float sa = 0.f, sh = 0.f, sq = 0.f;
#pragma unroll 4
    for (int c = g; c < C_; c += 8) {
      float a = att_s[c][nn];
      sa += a; sh += a * s1_s[c]; sq += a * a * s2_s[c];
    }
#pragma unroll
    for (int o = 4; o > 0; o >>= 1) {
      sa += __shfl_xor(sa, o, 64);
      sh += __shfl_xor(sh, o, 64);
      sq += __shfl_xor(sq, o, 64);
    }
    if (g == 0) {
      float cnt = sa * hw + EPS_;
      float fmean = sh / cnt;
      float sqv = sq - 2.f * fmean * sh + fmean * fmean * ((float)C_ * hw);
      float fstd = sqrtf(fmaxf(sqv, 0.f) / cnt);
      float inv = 1.f / (fstd + EPS_);
      inv_s[nn] = inv; fmi_s[nn] = fmean * inv;
    }
  }
  __syncthreads();

  float Ac = 0.f, Bc = 0.f;
#pragma unroll
  for (int n = 0; n < N_; ++n) { float a = att_s[t][n]; Ac += a * inv_s[n]; Bc += a * fmi_s[n]; }
  Aout[b * C_ + t] = Ac; Bout[b * C_ + t] = Bc;
}

// ---------------- Kernel 4: out = x + sigma*((Wo x + bo)*A - B) -------------
// 512 threads (8 waves), grid (64, 8), LB(512,4) -> 2 blocks/CU.
// Round-5: 2 passes x 128 px (was 4 x 64) -> 3 barriers instead of 8; loads
// remapped to full 512-B contiguous segments (32 lanes x 16 B); transposed
// LDS tile 128x128 bf16 (32 KB) XOR-swizzled so ds_read_b128 frag reads are
// at the bank floor and s8v staging writes stay <=2x floor.
__global__ __launch_bounds__(512, 4) void k_out(
    const float* __restrict__ x, const u16* __restrict__ wo_bf,
    const float* __restrict__ bo, const float* __restrict__ Aws,
    const float* __restrict__ Bws, const float* __restrict__ sig,
    float* __restrict__ out) {
  const int b = blockIdx.y;
  __shared__ u16 Xt[128 * 128];    // 32768 B, row = pixel (256 B/row, swizzled)
  __shared__ float As[C_], Bs[C_], bos[C_];
  const int tid = threadIdx.x, lane = tid & 63, w = tid >> 6;  // wave 0..7
  const int n = lane & 15, q = lane >> 4;

  if (tid < C_) { As[tid] = Aws[b * C_ + tid]; Bs[tid] = Bws[b * C_ + tid]; bos[tid] = bo[tid]; }
  const float sg = sig[0];

  // per-wave Wo fragments: af[s] = Wo_bf16[16w+n][32s+8q .. +7]  (16 VGPRs)
  s8v af[4];
#pragma unroll
  for (int s = 0; s < 4; ++s)
    af[s] = *(const s8v*)(wo_bf + (16 * w + n) * C_ + 32 * s + 8 * q);

  const float* xb = x + (size_t)b * C_ * HW_;
  float* ob = out + (size_t)b * C_ * HW_;
  const int pqd = tid & 31;          // px-quad: px 4*pqd within the 128-px pass
  const int co  = tid >> 5;          // ch-octet: ch 8*co .. +7
  const int p0 = blockIdx.x * 256;
  char* lds = (char*)Xt;

  float4 v[8];
  const float* src0 = xb + (size_t)(8 * co) * HW_ + p0 + 4 * pqd;
#pragma unroll
  for (int r = 0; r < 8; ++r) v[r] = *(const float4*)(src0 + (size_t)r * HW_);

#pragma unroll 1
  for (int pt = 0; pt < 2; ++pt) {
    const int p = p0 + 128 * pt;
    // transpose + convert + LDS write: 4 s8v per thread (8 ch x 4 px)
    {
      const float* vf = (const float*)v;
#pragma unroll
      for (int pp = 0; pp < 4; ++pp) {
        const int row = 4 * pqd + pp;
        s8v s;
#pragma unroll
        for (int r = 0; r < 8; ++r) s[r] = (short)f2b(vf[4 * r + pp]);
        *(s8v*)(lds + row * 256 + ((16 * co) ^ ((row & 7) << 4))) = s;
      }
    }
    __syncthreads();
    if (pt == 0) {  // prefetch next 128-px pass under MFMA
      const float* src1 = src0 + 128;
#pragma unroll
      for (int r = 0; r < 8; ++r) v[r] = *(const float4*)(src1 + (size_t)r * HW_);
    }

    f4v acc[8];
#pragma unroll
    for (int p2 = 0; p2 < 8; ++p2) acc[p2] = (f4v){0.f, 0.f, 0.f, 0.f};
#pragma unroll
    for (int s = 0; s < 4; ++s) {
      const int off = 64 * s + 16 * q;
#pragma unroll
      for (int p2 = 0; p2 < 8; ++p2) {
        const int row = 16 * p2 + n;
        s8v bfr = *(const s8v*)(lds + row * 256 + (off ^ ((row & 7) << 4)));
        acc[p2] = __builtin_amdgcn_mfma_f32_16x16x32_bf16(af[s], bfr, acc[p2], 0, 0, 0);
      }
    }

#pragma unroll
    for (int p2 = 0; p2 < 8; ++p2)
#pragma unroll
      for (int r = 0; r < 4; ++r) {
        int o = 16 * w + 4 * q + r;
        size_t idx = (size_t)o * HW_ + p + 16 * p2 + n;
        float xo = acc[p2][r] + bos[o];
        ob[idx] = xb[idx] + sg * (xo * As[o] - Bs[o]);
      }
    if (pt == 0) __syncthreads();
  }
}

extern "C" void kernel_launch(void* const* d_in, const int* in_sizes, int n_in,
                              void* d_out, int out_size, void* d_ws, size_t ws_size,
                              hipStream_t stream) {
  (void)in_sizes; (void)n_in; (void)out_size; (void)ws_size;
  const float* x     = (const float*)d_in[0];
  const float* Wsa   = (const float*)d_in[1];
  const float* bsa   = (const float*)d_in[2];
  const float* Wr    = (const float*)d_in[3];
  const float* br    = (const float*)d_in[4];
  const float* kn    = (const float*)d_in[5];
  const float* Wo    = (const float*)d_in[6];
  const float* bo    = (const float*)d_in[7];
  const float* alpha = (const float*)d_in[8];
  const float* sigma = (const float*)d_in[9];
  float* out = (float*)d_out;
  float* ws  = (float*)d_ws;

  float* G        = ws;            // 131072
  float* sx       = ws + 131072;   // 1024
  float* diagR    = ws + 132096;   // 1024
  float* diagSA   = ws + 133120;   // 1024
  float* colsumSA = ws + 134144;   // 1024
  float* diagO    = ws + 135168;   // 1024
  float* prv      = ws + 136192;   // 1024
  float* psav     = ws + 137216;   // 1024
  float* pov      = ws + 138240;   // 1024
  float* rel      = ws + 139264;   // 16384
  float* diagN    = ws + 155648;   // 128
  float* ksx      = ws + 155776;   // 128
  float* u        = ws + 155904;   // 128
  float* Aw       = ws + 156032;   // 1024
  float* Bw       = ws + 157056;   // 1024
  u16*   wo_bf    = (u16*)(ws + 158080);  // 16384 u16 = 8192 floats

  // d_out doubles as scratch for Gram partials until k_out overwrites it:
  float* pbuf = out;               // 64*8*16384 = 8388608 floats
  float* psx  = out + 8388608;     // 64*8*128   = 65536 floats

  k_gram<<<dim3(65, 8), 512, 0, stream>>>(x, pbuf, psx, Wsa, kn, Wo, u,
      out + (size_t)B_ * C_ * HW_, wo_bf);
  k_greduce<<<264, 128, 0, stream>>>((const float4*)pbuf, psx, (float4*)G, sx);
  k_cols<<<dim3(144, 8), 64, 0, stream>>>(G, sx, Wr, Wsa, Wo, kn, u,
      diagR, diagSA, colsumSA, diagO, prv, psav, pov, rel, diagN, ksx);
  k_asm<<<8, 128, 0, stream>>>(diagR, diagSA, colsumSA, diagO, prv, psav, pov,
      rel, diagN, ksx, br, bo, bsa, alpha, Aw, Bw);
  k_out<<<dim3(64, 8), 512, 0, stream>>>(x, wo_bf, bo, Aw, Bw, sigma, out);
}

// Round 2
// 188.414 us; speedup vs baseline: 1.1179x; 1.1179x over previous
//
#include <hip/hip_runtime.h>
#include <hip/hip_bf16.h>

#define B_   8
#define C_   128
#define HW_  16384
#define N_   16
#define EPS_ 1e-7f

typedef unsigned short u16;
typedef __attribute__((ext_vector_type(8))) short s8v;
typedef __attribute__((ext_vector_type(4))) short s4v;
typedef __attribute__((ext_vector_type(4))) float f4v;

__device__ __forceinline__ u16 f2b(float f) {
  union { __hip_bfloat16 b; u16 u; } cv; cv.b = __float2bfloat16(f); return cv.u;
}
__device__ __forceinline__ float b2f(u16 u) {
  union { float f; unsigned int i; } cv; cv.i = ((unsigned int)u) << 16; return cv.f;
}
__device__ __forceinline__ float wredsum(float v) {
#pragma unroll
  for (int o = 32; o > 0; o >>= 1) v += __shfl_xor(v, o, 64);
  return v;
}
__device__ __forceinline__ float wredmax(float v) {
#pragma unroll
  for (int o = 32; o > 0; o >>= 1) v = fmaxf(v, __shfl_xor(v, o, 64));
  return v;
}

// ---------------- Kernel 1: per-batch partial Gram + fused misc -------------
// PROVEN round-0 version (182 us total): 512 threads (8 waves), grid (65, 8),
// LB(512,4) -> 2 blocks/CU = 16 waves/CU. Wave w computes the 32x64 G quadrant
// rows (w&3)*32, cols (w>>2)*64. blockIdx.x==64 -> misc (u, orth, Wo->bf16).
#define XS_ 132  // LDS row stride in u16 (264 B): staging writes 2-way, reads ~2-way
__global__ __launch_bounds__(512, 4) void k_gram(
    const float* __restrict__ x, float* __restrict__ pbuf, float* __restrict__ psx,
    const float* __restrict__ Wsa, const float* __restrict__ kn,
    const float* __restrict__ Wo, float* __restrict__ u,
    float* __restrict__ loss_out, u16* __restrict__ wo_bf) {
  __shared__ u16 Xb[C_ * XS_];
  const int tid = threadIdx.x;
  const int b = blockIdx.y;

  if (blockIdx.x == 64) {  // ---- misc blocks ----
    if (b == 0) {          // u[r] = column sums of Wsa
      if (tid < C_) {
        float s = 0.f;
        for (int i = 0; i < C_; ++i) s += Wsa[i * C_ + tid];
        u[tid] = s;
      }
    } else if (b == 1) {   // orth loss (first 256 threads compute)
      float* smf = (float*)Xb;          // [0..15]=nrm, [16..23]=per-wave partials
      const int i = tid >> 4, j = tid & 15;
      float s = 0.f;
      if (tid < 256) {
        for (int c = 0; c < C_; ++c) s += kn[i * C_ + c] * kn[j * C_ + c];
        if (i == j) smf[i] = sqrtf(s);
      }
      __syncthreads();
      float l2 = 0.f;
      if (tid < 256) {
        float l = s / (smf[i] * smf[j] + EPS_) - (i == j ? 1.f : 0.f);
        l2 = l * l;
      }
      float wv = wredsum(l2);
      if ((tid & 63) == 0) smf[16 + (tid >> 6)] = wv;
      __syncthreads();
      if (tid == 0) {
        float t = 0.f;
        for (int k = 0; k < 8; ++k) t += smf[16 + k];
        loss_out[0] = 0.1f * logf(t + 1.f);
      }
    } else if (b == 2) {   // Wo -> bf16
#pragma unroll
      for (int j = 0; j < 8; ++j) {
        int f = tid + 512 * j;
        float4 v = ((const float4*)Wo)[f];
        s4v s; s[0] = (short)f2b(v.x); s[1] = (short)f2b(v.y);
        s[2] = (short)f2b(v.z); s[3] = (short)f2b(v.w);
        ((s4v*)wo_bf)[f] = s;
      }
    }
    return;
  }

  const int p0 = blockIdx.x * 256;
  const int lane = tid & 63;
  const int w = tid >> 6;                 // wave 0..7
  const int m = lane & 15, q = lane >> 4;
  const int rb = (w & 3) * 32, cb = (w >> 2) * 64;

  f4v acc[2][4];
#pragma unroll
  for (int a = 0; a < 2; ++a)
#pragma unroll
    for (int c2 = 0; c2 < 4; ++c2) acc[a][c2] = (f4v){0.f, 0.f, 0.f, 0.f};

  float sxp = 0.f;
  const float* xb = x + (size_t)b * C_ * HW_;
  const float* ro = xb + (size_t)(tid >> 5) * HW_ + p0 + 4 * (tid & 31);

  float4 v[8];
#pragma unroll
  for (int j = 0; j < 8; ++j) v[j] = *(const float4*)(ro + (size_t)(16 * j) * HW_);

#pragma unroll
  for (int t = 0; t < 2; ++t) {
    // convert + LDS write (rows c = (tid>>5)+16j, cols 4*(tid&31))
#pragma unroll
    for (int j = 0; j < 8; ++j) {
      int c = (tid >> 5) + 16 * j;
      s4v s; s[0] = (short)f2b(v[j].x); s[1] = (short)f2b(v[j].y);
      s[2] = (short)f2b(v[j].z); s[3] = (short)f2b(v[j].w);
      *(s4v*)(&Xb[c * XS_ + 4 * (tid & 31)]) = s;
    }
    __syncthreads();
    if (t == 0) {  // prefetch tile 1 under tile-0 compute
#pragma unroll
      for (int j = 0; j < 8; ++j) v[j] = *(const float4*)(ro + (size_t)(16 * j) * HW_ + 128);
    }
    if (tid < C_) {
#pragma unroll
      for (int kk = 0; kk < 16; ++kk) {
        s8v vv = *(const s8v*)(&Xb[tid * XS_ + 8 * kk]);
#pragma unroll
        for (int e = 0; e < 8; ++e) sxp += b2f((u16)vv[e]);
      }
    }
#pragma unroll
    for (int s = 0; s < 4; ++s) {
      const int k0 = 32 * s;
      s8v Af[2], Bf[4];
#pragma unroll
      for (int a = 0; a < 2; ++a)
        Af[a] = *(const s8v*)(&Xb[(rb + 16 * a + m) * XS_ + k0 + 8 * q]);
#pragma unroll
      for (int c2 = 0; c2 < 4; ++c2)
        Bf[c2] = *(const s8v*)(&Xb[(cb + 16 * c2 + m) * XS_ + k0 + 8 * q]);
#pragma unroll
      for (int a = 0; a < 2; ++a)
#pragma unroll
        for (int c2 = 0; c2 < 4; ++c2)
          acc[a][c2] = __builtin_amdgcn_mfma_f32_16x16x32_bf16(Af[a], Bf[c2], acc[a][c2], 0, 0, 0);
    }
    __syncthreads();
  }

  float* pg = pbuf + ((size_t)(blockIdx.x * B_ + b) << 14);
#pragma unroll
  for (int a = 0; a < 2; ++a)
#pragma unroll
    for (int c2 = 0; c2 < 4; ++c2)
#pragma unroll
      for (int r = 0; r < 4; ++r) {
        int row = rb + 16 * a + 4 * q + r;  // C/D: row=(lane>>4)*4+reg
        int col = cb + 16 * c2 + m;         //      col=lane&15
        pg[row * C_ + col] = acc[a][c2][r];
      }
  if (tid < C_) psx[(blockIdx.x * B_ + b) * C_ + tid] = sxp;
}

// ---------------- reduce 64 partials -> G, sx (float4) ----------------------
// 264 blocks x 128 threads -> all 256 CUs active, same total wave count.
__global__ __launch_bounds__(128) void k_greduce(const float4* __restrict__ pbuf4,
                                                 const float* __restrict__ psx,
                                                 float4* __restrict__ G4,
                                                 float* __restrict__ sx) {
  const int blk = blockIdx.x;
  if (blk < 256) {
    const int gid = blk * 128 + threadIdx.x;  // [0, 32768)
    const int b = gid >> 12, idx4 = gid & 4095;
    float4 s = {0.f, 0.f, 0.f, 0.f};
#pragma unroll 16
    for (int ch = 0; ch < 64; ++ch) {
      float4 p = pbuf4[((size_t)(ch * B_ + b) << 12) + idx4];
      s.x += p.x; s.y += p.y; s.z += p.z; s.w += p.w;
    }
    G4[gid] = s;
  } else {
    const int tt = (blk - 256) * 128 + threadIdx.x;  // [0, 1024)
    const int b = tt >> 7, c = tt & 127;
    float s = 0.f;
#pragma unroll 16
    for (int ch = 0; ch < 64; ++ch) s += psx[(ch * B_ + b) * C_ + c];
    sx[tt] = s;
  }
}

// ---------------- Kernel 2: per-(batch, column) G-derived quantities --------
__global__ __launch_bounds__(64) void k_cols(
    const float* __restrict__ G, const float* __restrict__ sx,
    const float* __restrict__ Wr, const float* __restrict__ Wsa,
    const float* __restrict__ Wo, const float* __restrict__ kn,
    const float* __restrict__ u,
    float* diagR, float* diagSA, float* colsumSA, float* diagO,
    float* prv, float* psav, float* pov, float* rel, float* diagN, float* ksx) {
  const int b = blockIdx.y;
  const int col = blockIdx.x;
  const int lane = threadIdx.x;
  const float* Gb = G + b * C_ * C_;
  const float4* g0 = (const float4*)(Gb + lane * C_);
  const float4* g1 = (const float4*)(Gb + (64 + lane) * C_);
  const float sx0 = sx[b * C_ + lane], sx1 = sx[b * C_ + 64 + lane];

  if (col < C_) {
    const float4* wr = (const float4*)(Wr + col * C_);
    const float4* wa = (const float4*)(Wsa + col * C_);
    const float4* wo = (const float4*)(Wo + col * C_);
    float t0r = 0, t1r = 0, t0a = 0, t1a = 0, t0o = 0, t1o = 0;
    for (int c = 0; c < 32; ++c) {
      float4 a0 = g0[c], a1 = g1[c];
      float4 vr = wr[c], va = wa[c], vo = wo[c];
      t0r += a0.x * vr.x + a0.y * vr.y + a0.z * vr.z + a0.w * vr.w;
      t1r += a1.x * vr.x + a1.y * vr.y + a1.z * vr.z + a1.w * vr.w;
      t0a += a0.x * va.x + a0.y * va.y + a0.z * va.z + a0.w * va.w;
      t1a += a1.x * va.x + a1.y * va.y + a1.z * va.z + a1.w * va.w;
      t0o += a0.x * vo.x + a0.y * vo.y + a0.z * vo.z + a0.w * vo.w;
      t1o += a1.x * vo.x + a1.y * vo.y + a1.z * vo.z + a1.w * vo.w;
    }
    float wr0 = Wr[col * C_ + lane], wr1 = Wr[col * C_ + 64 + lane];
    float wa0 = Wsa[col * C_ + lane], wa1 = Wsa[col * C_ + 64 + lane];
    float wo0 = Wo[col * C_ + lane], wo1 = Wo[col * C_ + 64 + lane];
    float u0 = u[lane], u1 = u[64 + lane];
    float dR = wredsum(wr0 * t0r + wr1 * t1r);
    float pR = wredsum(wr0 * sx0 + wr1 * sx1);
    float dA = wredsum(wa0 * t0a + wa1 * t1a);
    float cA = wredsum(u0 * t0a + u1 * t1a);
    float pA = wredsum(wa0 * sx0 + wa1 * sx1);
    float dO = wredsum(wo0 * t0o + wo1 * t1o);
    float pO = wredsum(wo0 * sx0 + wo1 * sx1);
    float rl[N_];
#pragma unroll
    for (int n = 0; n < N_; ++n)
      rl[n] = wredsum(kn[n * C_ + lane] * t0r + kn[n * C_ + 64 + lane] * t1r);
    if (lane == 0) {
      diagR[b * C_ + col] = dR;  prv[b * C_ + col] = pR;
      diagSA[b * C_ + col] = dA; colsumSA[b * C_ + col] = cA; psav[b * C_ + col] = pA;
      diagO[b * C_ + col] = dO;  pov[b * C_ + col] = pO;
      for (int n = 0; n < N_; ++n) rel[(b * N_ + n) * C_ + col] = rl[n];
    }
  } else {
    const int n = col - C_;
    const float4* wk = (const float4*)(kn + n * C_);
    float t0 = 0, t1 = 0;
    for (int c = 0; c < 32; ++c) {
      float4 a0 = g0[c], a1 = g1[c], vk = wk[c];
      t0 += a0.x * vk.x + a0.y * vk.y + a0.z * vk.z + a0.w * vk.w;
      t1 += a1.x * vk.x + a1.y * vk.y + a1.z * vk.z + a1.w * vk.w;
    }
    float k0v = kn[n * C_ + lane], k1v = kn[n * C_ + 64 + lane];
    float dN = wredsum(k0v * t0 + k1v * t1);
    float kx = wredsum(k0v * sx0 + k1v * sx1);
    if (lane == 0) { diagN[b * N_ + n] = dN; ksx[b * N_ + n] = kx; }
  }
}

// ---------------- Kernel 3: per-batch assembly -> c1[b,c], c0[b,c] ----------
// Outputs folded epilogue coefficients: c1 = sigma*A, c0 = sigma*(A*bo - B)
// so k_out's epilogue is out = x + c1*acc + c0 (no bo/sigma needed there).
__global__ __launch_bounds__(128) void k_asm(
    const float* diagR, const float* diagSA, const float* colsumSA, const float* diagO,
    const float* prv, const float* psav, const float* pov,
    const float* rel, const float* diagN, const float* ksx,
    const float* br, const float* bo, const float* bsa, const float* alpha,
    const float* sigma, float* C1out, float* C0out) {
  const int b = blockIdx.x;
  const int t = threadIdx.x;
  __shared__ float rb2[2];
  __shared__ float att_s[C_][N_ + 1];
  __shared__ float s1_s[C_], s2_s[C_];
  __shared__ float inv_s[N_], fmi_s[N_];
  const float hw = (float)HW_;
  const float bsa_c = bsa[t], br_c = br[t], bo_c = bo[t];
  const float psa_c = psav[b * C_ + t], pr_c = prv[b * C_ + t], po_c = pov[b * C_ + t];

  float bsum, psum, mx, ssum;
  { float wv = wredsum(bsa_c); if ((t & 63) == 0) rb2[t >> 6] = wv; __syncthreads();
    bsum = rb2[0] + rb2[1]; __syncthreads(); }
  { float wv = wredsum(psa_c); if ((t & 63) == 0) rb2[t >> 6] = wv; __syncthreads();
    psum = rb2[0] + rb2[1]; __syncthreads(); }

  const float nxr = sqrtf(fmaxf(diagR[b * C_ + t] + 2.f * br_c * pr_c + hw * br_c * br_c, 0.f));
  s1_s[t] = po_c + hw * bo_c;
  s2_s[t] = diagO[b * C_ + t] + 2.f * bo_c * po_c + hw * bo_c * bo_c;
  const float colsum = colsumSA[b * C_ + t] + bsum * psa_c + bsa_c * (psum + hw * bsum);
  const float diagv = diagSA[b * C_ + t] + 2.f * bsa_c * psa_c + hw * bsa_c * bsa_c;
  const float fm = (colsum - diagv) * (1.f / (float)C_);

  { float wv = wredmax(fm); if ((t & 63) == 0) rb2[t >> 6] = wv; __syncthreads();
    mx = fmaxf(rb2[0], rb2[1]); __syncthreads(); }
  const float ee = expf(fm - mx);
  { float wv = wredsum(ee); if ((t & 63) == 0) rb2[t >> 6] = wv; __syncthreads();
    ssum = rb2[0] + rb2[1]; __syncthreads(); }
  const float reg = ee / ssum;

  float r[N_];
  float rmax = -1e30f;
#pragma unroll
  for (int n = 0; n < N_; ++n) {
    float al = fminf(fmaxf(alpha[n], 0.f), 1.f);
    float nxn = sqrtf(fmaxf(diagN[b * N_ + n], 0.f));
    float rv = (rel[(b * N_ + n) * C_ + t] + br_c * ksx[b * N_ + n]) / (nxn * nxr + EPS_) + al * reg;
    r[n] = rv; rmax = fmaxf(rmax, rv);
  }
  float es = 0.f;
#pragma unroll
  for (int n = 0; n < N_; ++n) { r[n] = expf(r[n] - rmax); es += r[n]; }
  const float ies = 1.f / es;
#pragma unroll
  for (int n = 0; n < N_; ++n) att_s[t][n] = r[n] * ies;
  __syncthreads();

  {
    const int nn = t >> 3, g = t & 7;     // 8 lanes per class n
    float sa = 0.f, sh = 0.f, sq = 0.f;
#pragma unroll 4
    for (int c = g; c < C_; c += 8) {
      float a = att_s[c][nn];
      sa += a; sh += a * s1_s[c]; sq += a * a * s2_s[c];
    }
#pragma unroll
    for (int o = 4; o > 0; o >>= 1) {
      sa += __shfl_xor(sa, o, 64);
      sh += __shfl_xor(sh, o, 64);
      sq += __shfl_xor(sq, o, 64);
    }
    if (g == 0) {
      float cnt = sa * hw + EPS_;
      float fmean = sh / cnt;
      float sqv = sq - 2.f * fmean * sh + fmean * fmean * ((float)C_ * hw);
      float fstd = sqrtf(fmaxf(sqv, 0.f) / cnt);
      float inv = 1.f / (fstd + EPS_);
      inv_s[nn] = inv; fmi_s[nn] = fmean * inv;
    }
  }
  __syncthreads();

  float Ac = 0.f, Bc = 0.f;
#pragma unroll
  for (int n = 0; n < N_; ++n) { float a = att_s[t][n]; Ac += a * inv_s[n]; Bc += a * fmi_s[n]; }
  const float sg = sigma[0];
  C1out[b * C_ + t] = sg * Ac;
  C0out[b * C_ + t] = sg * (Ac * bo_c - Bc);
}

// ---------------- Kernel 4: out = x + c1[c]*(Wo x)[c,p] + c0[c] -------------
// 512 threads, grid (128, 8): ONE 128-px tile per block. Round-6 redesign:
//  - swizzle f(row) = (row ^ (row>>2)) & 7 applied to byte bits 4-6: bijective
//    over every 8 consecutive values of BOTH write rows (4*l+pp) and read rows
//    (16*p2+n) -> all 4 LDS patterns conflict-free (round-5's (row&7) swizzle
//    collapsed the staging write to 2 slots/half-wave = 1.8M conflicts).
//  - x stays in registers; MFMA acc routed through a 64 KB fp32 LDS buffer
//    (union with the dead bf16 tile) back to staging layout -> NO second x
//    fetch from HBM and fully-coalesced float4 stores (round-5 k_out showed
//    FETCH 95.6 MB / WRITE 113.7 MB vs 67 MB ideal each).
// LDS 64 KB + nothing else -> 2 blocks/CU at LB(512,4).
__global__ __launch_bounds__(512, 4) void k_out(
    const float* __restrict__ x, const u16* __restrict__ wo_bf,
    const float* __restrict__ c1g, const float* __restrict__ c0g,
    float* __restrict__ out) {
  __shared__ f4v smem4[4096];      // 65536 B union: bf16 X^T tile, then fp32 acc
  char* lds = (char*)smem4;
  const int b = blockIdx.y;
  const int tid = threadIdx.x, lane = tid & 63, w = tid >> 6;  // wave 0..7
  const int n = lane & 15, q = lane >> 4;
  const int co = tid >> 5;           // ch-octet 0..15 (ch 8co..8co+7)
  const int l  = tid & 31;           // px-quad  0..31 (px 4l..4l+3)
  const int p0 = blockIdx.x * 128;

  // per-wave Wo fragments: af[s] = Wo_bf16[16w+n][32s+8q .. +7]
  s8v af[4];
#pragma unroll
  for (int s = 0; s < 4; ++s)
    af[s] = *(const s8v*)(wo_bf + (16 * w + n) * C_ + 32 * s + 8 * q);

  // epilogue coefficients for this thread's 8 channels
  float c1[8], c0[8];
#pragma unroll
  for (int r = 0; r < 8; ++r) {
    c1[r] = c1g[b * C_ + 8 * co + r];
    c0[r] = c0g[b * C_ + 8 * co + r];
  }

  const float* xb = x + (size_t)b * C_ * HW_;
  float* ob = out + (size_t)b * C_ * HW_;

  // load x: 8 ch x 4 px per thread, 512-B contiguous segments per half-wave
  float4 v[8];
  const float* src = xb + (size_t)(8 * co) * HW_ + p0 + 4 * l;
#pragma unroll
  for (int r = 0; r < 8; ++r) v[r] = *(const float4*)(src + (size_t)r * HW_);

  // stage transposed bf16 tile: row = px-local (256 B of ch), swizzled
  {
    const float* vf = (const float*)v;
#pragma unroll
    for (int pp = 0; pp < 4; ++pp) {
      const int row = 4 * l + pp;
      s8v s;
#pragma unroll
      for (int r = 0; r < 8; ++r) s[r] = (short)f2b(vf[4 * r + pp]);
      *(s8v*)(lds + row * 256 + ((16 * co) ^ (((row ^ (row >> 2)) & 7) << 4))) = s;
    }
  }
  __syncthreads();

  // MFMA: wave w -> o-rows 16w..16w+15, all 128 px
  f4v acc[8];
#pragma unroll
  for (int p2 = 0; p2 < 8; ++p2) acc[p2] = (f4v){0.f, 0.f, 0.f, 0.f};
#pragma unroll
  for (int s = 0; s < 4; ++s) {
#pragma unroll
    for (int p2 = 0; p2 < 8; ++p2) {
      const int row = 16 * p2 + n;
      s8v bfr = *(const s8v*)(lds + row * 256 +
                              ((64 * s + 16 * q) ^ (((row ^ (row >> 2)) & 7) << 4)));
      acc[p2] = __builtin_amdgcn_mfma_f32_16x16x32_bf16(af[s], bfr, acc[p2], 0, 0, 0);
    }
  }
  __syncthreads();   // bf16 tile dead; reuse smem as fp32 acc buffer

  // acc -> LDS fp32 [px][o] (512 B/row), swizzled; quad o = 16w+4q .. +3
#pragma unroll
  for (int p2 = 0; p2 < 8; ++p2) {
    const int px = 16 * p2 + n;
    *(f4v*)(lds + px * 512 + ((64 * w + 16 * q) ^ (((px ^ (px >> 2)) & 7) << 4))) = acc[p2];
  }
  __syncthreads();

  // readback in staging layout + epilogue + coalesced float4 stores
  f4v ra[4], rb_[4];   // ra[pp] = acc ch 8co..+3 at px 4l+pp; rb_ = ch 8co+4..+7
#pragma unroll
  for (int pp = 0; pp < 4; ++pp) {
    const int px = 4 * l + pp;
    const int g = ((px ^ (px >> 2)) & 7) << 4;
    ra[pp]  = *(const f4v*)(lds + px * 512 + ((32 * co) ^ g));
    rb_[pp] = *(const f4v*)(lds + px * 512 + ((32 * co + 16) ^ g));
  }
  float* obp = ob + (size_t)(8 * co) * HW_ + p0 + 4 * l;
#pragma unroll
  for (int r = 0; r < 4; ++r) {
    float4 o4;
    o4.x = v[r].x + c1[r] * ra[0][r] + c0[r];
    o4.y = v[r].y + c1[r] * ra[1][r] + c0[r];
    o4.z = v[r].z + c1[r] * ra[2][r] + c0[r];
    o4.w = v[r].w + c1[r] * ra[3][r] + c0[r];
    *(float4*)(obp + (size_t)r * HW_) = o4;
  }
#pragma unroll
  for (int r = 0; r < 4; ++r) {
    float4 o4;
    o4.x = v[4 + r].x + c1[4 + r] * rb_[0][r] + c0[4 + r];
    o4.y = v[4 + r].y + c1[4 + r] * rb_[1][r] + c0[4 + r];
    o4.z = v[4 + r].z + c1[4 + r] * rb_[2][r] + c0[4 + r];
    o4.w = v[4 + r].w + c1[4 + r] * rb_[3][r] + c0[4 + r];
    *(float4*)(obp + (size_t)(4 + r) * HW_) = o4;
  }
}

extern "C" void kernel_launch(void* const* d_in, const int* in_sizes, int n_in,
                              void* d_out, int out_size, void* d_ws, size_t ws_size,
                              hipStream_t stream) {
  (void)in_sizes; (void)n_in; (void)out_size; (void)ws_size;
  const float* x     = (const float*)d_in[0];
  const float* Wsa   = (const float*)d_in[1];
  const float* bsa   = (const float*)d_in[2];
  const float* Wr    = (const float*)d_in[3];
  const float* br    = (const float*)d_in[4];
  const float* kn    = (const float*)d_in[5];
  const float* Wo    = (const float*)d_in[6];
  const float* bo    = (const float*)d_in[7];
  const float* alpha = (const float*)d_in[8];
  const float* sigma = (const float*)d_in[9];
  float* out = (float*)d_out;
  float* ws  = (float*)d_ws;

  float* G        = ws;            // 131072
  float* sx       = ws + 131072;   // 1024
  float* diagR    = ws + 132096;   // 1024
  float* diagSA   = ws + 133120;   // 1024
  float* colsumSA = ws + 134144;   // 1024
  float* diagO    = ws + 135168;   // 1024
  float* prv      = ws + 136192;   // 1024
  float* psav     = ws + 137216;   // 1024
  float* pov      = ws + 138240;   // 1024
  float* rel      = ws + 139264;   // 16384
  float* diagN    = ws + 155648;   // 128
  float* ksx      = ws + 155776;   // 128
  float* u        = ws + 155904;   // 128
  float* C1w      = ws + 156032;   // 1024
  float* C0w      = ws + 157056;   // 1024
  u16*   wo_bf    = (u16*)(ws + 158080);  // 16384 u16 = 8192 floats

  // d_out doubles as scratch for Gram partials until k_out overwrites it:
  float* pbuf = out;               // 64*8*16384 = 8388608 floats
  float* psx  = out + 8388608;     // 64*8*128   = 65536 floats

  k_gram<<<dim3(65, 8), 512, 0, stream>>>(x, pbuf, psx, Wsa, kn, Wo, u,
      out + (size_t)B_ * C_ * HW_, wo_bf);
  k_greduce<<<264, 128, 0, stream>>>((const float4*)pbuf, psx, (float4*)G, sx);
  k_cols<<<dim3(144, 8), 64, 0, stream>>>(G, sx, Wr, Wsa, Wo, kn, u,
      diagR, diagSA, colsumSA, diagO, prv, psav, pov, rel, diagN, ksx);
  k_asm<<<8, 128, 0, stream>>>(diagR, diagSA, colsumSA, diagO, prv, psav, pov,
      rel, diagN, ksx, br, bo, bsa, alpha, sigma, C1w, C0w);
  k_out<<<dim3(128, 8), 512, 0, stream>>>(x, wo_bf, C1w, C0w, out);
}

// Round 3
// 185.809 us; speedup vs baseline: 1.1336x; 1.0140x over previous
//
#include <hip/hip_runtime.h>
#include <hip/hip_bf16.h>

#define B_   8
#define C_   128
#define HW_  16384
#define N_   16
#define EPS_ 1e-7f

typedef unsigned short u16;
typedef __attribute__((ext_vector_type(8))) short s8v;
typedef __attribute__((ext_vector_type(4))) short s4v;
typedef __attribute__((ext_vector_type(4))) float f4v;

__device__ __forceinline__ u16 f2b(float f) {
  union { __hip_bfloat16 b; u16 u; } cv; cv.b = __float2bfloat16(f); return cv.u;
}
__device__ __forceinline__ float b2f(u16 u) {
  union { float f; unsigned int i; } cv; cv.i = ((unsigned int)u) << 16; return cv.f;
}
__device__ __forceinline__ float wredsum(float v) {
#pragma unroll
  for (int o = 32; o > 0; o >>= 1) v += __shfl_xor(v, o, 64);
  return v;
}
__device__ __forceinline__ float wredmax(float v) {
#pragma unroll
  for (int o = 32; o > 0; o >>= 1) v = fmaxf(v, __shfl_xor(v, o, 64));
  return v;
}

// ---------------- Kernel 1: per-batch partial Gram + fused misc -------------
// Round-0 proven structure (2-pass, padded LDS) with two surgical fixes:
//  - sx computed from the fp32 values already in registers (32-lane shuffle
//    reduce) instead of a 256-op serial bf16 LDS re-walk on threads<128 that
//    put waves 0-1 on the critical path of every barrier.
//  - pbuf stored in MFMA-NATIVE layout [w][reg-quad j][lane] as f4v: each
//    store instruction is 64 lanes x 16 B fully contiguous (1024-B segments)
//    vs the old 4-B scatter (64-B segments ~1.7x write waste, 64 instrs).
//    pbuf is internal; k_greduce decodes the layout when writing G.
#define XS_ 132  // LDS row stride in u16 (264 B)
__global__ __launch_bounds__(512, 4) void k_gram(
    const float* __restrict__ x, float* __restrict__ pbuf, float* __restrict__ psx,
    const float* __restrict__ Wsa, const float* __restrict__ kn,
    const float* __restrict__ Wo, float* __restrict__ u,
    float* __restrict__ loss_out, u16* __restrict__ wo_bf) {
  __shared__ u16 Xb[C_ * XS_];
  const int tid = threadIdx.x;
  const int b = blockIdx.y;

  if (blockIdx.x == 64) {  // ---- misc blocks ----
    if (b == 0) {          // u[r] = column sums of Wsa
      if (tid < C_) {
        float s = 0.f;
        for (int i = 0; i < C_; ++i) s += Wsa[i * C_ + tid];
        u[tid] = s;
      }
    } else if (b == 1) {   // orth loss (first 256 threads compute)
      float* smf = (float*)Xb;          // [0..15]=nrm, [16..23]=per-wave partials
      const int i = tid >> 4, j = tid & 15;
      float s = 0.f;
      if (tid < 256) {
        for (int c = 0; c < C_; ++c) s += kn[i * C_ + c] * kn[j * C_ + c];
        if (i == j) smf[i] = sqrtf(s);
      }
      __syncthreads();
      float l2 = 0.f;
      if (tid < 256) {
        float l = s / (smf[i] * smf[j] + EPS_) - (i == j ? 1.f : 0.f);
        l2 = l * l;
      }
      float wv = wredsum(l2);
      if ((tid & 63) == 0) smf[16 + (tid >> 6)] = wv;
      __syncthreads();
      if (tid == 0) {
        float t = 0.f;
        for (int k = 0; k < 8; ++k) t += smf[16 + k];
        loss_out[0] = 0.1f * logf(t + 1.f);
      }
    } else if (b == 2) {   // Wo -> bf16
#pragma unroll
      for (int j = 0; j < 8; ++j) {
        int f = tid + 512 * j;
        float4 v = ((const float4*)Wo)[f];
        s4v s; s[0] = (short)f2b(v.x); s[1] = (short)f2b(v.y);
        s[2] = (short)f2b(v.z); s[3] = (short)f2b(v.w);
        ((s4v*)wo_bf)[f] = s;
      }
    }
    return;
  }

  const int p0 = blockIdx.x * 256;
  const int lane = tid & 63;
  const int w = tid >> 6;                 // wave 0..7
  const int m = lane & 15, q = lane >> 4;
  const int rb = (w & 3) * 32, cb = (w >> 2) * 64;

  f4v acc[2][4];
#pragma unroll
  for (int a = 0; a < 2; ++a)
#pragma unroll
    for (int c2 = 0; c2 < 4; ++c2) acc[a][c2] = (f4v){0.f, 0.f, 0.f, 0.f};

  const float* xb = x + (size_t)b * C_ * HW_;
  const float* ro = xb + (size_t)(tid >> 5) * HW_ + p0 + 4 * (tid & 31);

  float4 v[8];
#pragma unroll
  for (int j = 0; j < 8; ++j) v[j] = *(const float4*)(ro + (size_t)(16 * j) * HW_);

  float rs[8];
#pragma unroll
  for (int t = 0; t < 2; ++t) {
    // convert + LDS write (rows c = (tid>>5)+16j, cols 4*(tid&31)) + row sums
#pragma unroll
    for (int j = 0; j < 8; ++j) {
      int c = (tid >> 5) + 16 * j;
      s4v s; s[0] = (short)f2b(v[j].x); s[1] = (short)f2b(v[j].y);
      s[2] = (short)f2b(v[j].z); s[3] = (short)f2b(v[j].w);
      *(s4v*)(&Xb[c * XS_ + 4 * (tid & 31)]) = s;
      float rsum = v[j].x + v[j].y + v[j].z + v[j].w;
      if (t == 0) rs[j] = rsum; else rs[j] += rsum;
    }
    __syncthreads();
    if (t == 0) {  // prefetch tile 1 under tile-0 compute
#pragma unroll
      for (int j = 0; j < 8; ++j) v[j] = *(const float4*)(ro + (size_t)(16 * j) * HW_ + 128);
    }
#pragma unroll
    for (int s = 0; s < 4; ++s) {
      const int k0 = 32 * s;
      s8v Af[2], Bf[4];
#pragma unroll
      for (int a = 0; a < 2; ++a)
        Af[a] = *(const s8v*)(&Xb[(rb + 16 * a + m) * XS_ + k0 + 8 * q]);
#pragma unroll
      for (int c2 = 0; c2 < 4; ++c2)
        Bf[c2] = *(const s8v*)(&Xb[(cb + 16 * c2 + m) * XS_ + k0 + 8 * q]);
#pragma unroll
      for (int a = 0; a < 2; ++a)
#pragma unroll
        for (int c2 = 0; c2 < 4; ++c2)
          acc[a][c2] = __builtin_amdgcn_mfma_f32_16x16x32_bf16(Af[a], Bf[c2], acc[a][c2], 0, 0, 0);
    }
    __syncthreads();
  }

  // pbuf in MFMA-native layout: float4 slot (w*8 + a*4 + c2)*64 + lane
  float4* pg4 = (float4*)pbuf + ((size_t)(blockIdx.x * B_ + b) << 12);
#pragma unroll
  for (int a = 0; a < 2; ++a)
#pragma unroll
    for (int c2 = 0; c2 < 4; ++c2) {
      float4 o4; o4.x = acc[a][c2][0]; o4.y = acc[a][c2][1];
      o4.z = acc[a][c2][2]; o4.w = acc[a][c2][3];
      pg4[(w * 8 + a * 4 + c2) * 64 + lane] = o4;
    }

  // sx: 32-lane shuffle reduce (lanes sharing tid>>5 own the same 8 rows)
#pragma unroll
  for (int o = 16; o > 0; o >>= 1)
#pragma unroll
    for (int j = 0; j < 8; ++j) rs[j] += __shfl_xor(rs[j], o, 64);
  if ((tid & 31) == 0) {
#pragma unroll
    for (int j = 0; j < 8; ++j)
      psx[(blockIdx.x * B_ + b) * C_ + (tid >> 5) + 16 * j] = rs[j];
  }
}

// ---------------- reduce 64 partials -> G, sx ------------------------------
// Reads pbuf in the coalesced native layout; decodes (w,j,lane)->(row,col)
// only for the tiny G scatter (512 KB, L2-resident).
__global__ __launch_bounds__(128) void k_greduce(const float4* __restrict__ pbuf4,
                                                 const float* __restrict__ psx,
                                                 float* __restrict__ G,
                                                 float* __restrict__ sx) {
  const int blk = blockIdx.x;
  if (blk < 256) {
    const int gid = blk * 128 + threadIdx.x;  // [0, 32768)
    const int b = gid >> 12, i4 = gid & 4095;
    float4 s = {0.f, 0.f, 0.f, 0.f};
#pragma unroll 16
    for (int ch = 0; ch < 64; ++ch) {
      float4 p = pbuf4[((size_t)(ch * B_ + b) << 12) + i4];
      s.x += p.x; s.y += p.y; s.z += p.z; s.w += p.w;
    }
    const int w = i4 >> 9, j = (i4 >> 6) & 7, lane = i4 & 63;
    const int a = j >> 2, c2 = j & 3, q = lane >> 4, m = lane & 15;
    const int row0 = (w & 3) * 32 + 16 * a + 4 * q;
    const int col = (w >> 2) * 64 + 16 * c2 + m;
    float* Gp = G + b * C_ * C_ + row0 * C_ + col;
    Gp[0] = s.x; Gp[C_] = s.y; Gp[2 * C_] = s.z; Gp[3 * C_] = s.w;
  } else {
    const int tt = (blk - 256) * 128 + threadIdx.x;  // [0, 1024)
    const int b = tt >> 7, c = tt & 127;
    float s = 0.f;
#pragma unroll 16
    for (int ch = 0; ch < 64; ++ch) s += psx[(ch * B_ + b) * C_ + c];
    sx[tt] = s;
  }
}

// ---------------- Kernel 2: per-(batch, column) G-derived quantities --------
__global__ __launch_bounds__(64) void k_cols(
    const float* __restrict__ G, const float* __restrict__ sx,
    const float* __restrict__ Wr, const float* __restrict__ Wsa,
    const float* __restrict__ Wo, const float* __restrict__ kn,
    const float* __restrict__ u,
    float* diagR, float* diagSA, float* colsumSA, float* diagO,
    float* prv, float* psav, float* pov, float* rel, float* diagN, float* ksx) {
  const int b = blockIdx.y;
  const int col = blockIdx.x;
  const int lane = threadIdx.x;
  const float* Gb = G + b * C_ * C_;
  const float4* g0 = (const float4*)(Gb + lane * C_);
  const float4* g1 = (const float4*)(Gb + (64 + lane) * C_);
  const float sx0 = sx[b * C_ + lane], sx1 = sx[b * C_ + 64 + lane];

  if (col < C_) {
    const float4* wr = (const float4*)(Wr + col * C_);
    const float4* wa = (const float4*)(Wsa + col * C_);
    const float4* wo = (const float4*)(Wo + col * C_);
    float t0r = 0, t1r = 0, t0a = 0, t1a = 0, t0o = 0, t1o = 0;
    for (int c = 0; c < 32; ++c) {
      float4 a0 = g0[c], a1 = g1[c];
      float4 vr = wr[c], va = wa[c], vo = wo[c];
      t0r += a0.x * vr.x + a0.y * vr.y + a0.z * vr.z + a0.w * vr.w;
      t1r += a1.x * vr.x + a1.y * vr.y + a1.z * vr.z + a1.w * vr.w;
      t0a += a0.x * va.x + a0.y * va.y + a0.z * va.z + a0.w * va.w;
      t1a += a1.x * va.x + a1.y * va.y + a1.z * va.z + a1.w * va.w;
      t0o += a0.x * vo.x + a0.y * vo.y + a0.z * vo.z + a0.w * vo.w;
      t1o += a1.x * vo.x + a1.y * vo.y + a1.z * vo.z + a1.w * vo.w;
    }
    float wr0 = Wr[col * C_ + lane], wr1 = Wr[col * C_ + 64 + lane];
    float wa0 = Wsa[col * C_ + lane], wa1 = Wsa[col * C_ + 64 + lane];
    float wo0 = Wo[col * C_ + lane], wo1 = Wo[col * C_ + 64 + lane];
    float u0 = u[lane], u1 = u[64 + lane];
    float dR = wredsum(wr0 * t0r + wr1 * t1r);
    float pR = wredsum(wr0 * sx0 + wr1 * sx1);
    float dA = wredsum(wa0 * t0a + wa1 * t1a);
    float cA = wredsum(u0 * t0a + u1 * t1a);
    float pA = wredsum(wa0 * sx0 + wa1 * sx1);
    float dO = wredsum(wo0 * t0o + wo1 * t1o);
    float pO = wredsum(wo0 * sx0 + wo1 * sx1);
    float rl[N_];
#pragma unroll
    for (int n = 0; n < N_; ++n)
      rl[n] = wredsum(kn[n * C_ + lane] * t0r + kn[n * C_ + 64 + lane] * t1r);
    if (lane == 0) {
      diagR[b * C_ + col] = dR;  prv[b * C_ + col] = pR;
      diagSA[b * C_ + col] = dA; colsumSA[b * C_ + col] = cA; psav[b * C_ + col] = pA;
      diagO[b * C_ + col] = dO;  pov[b * C_ + col] = pO;
      for (int n = 0; n < N_; ++n) rel[(b * N_ + n) * C_ + col] = rl[n];
    }
  } else {
    const int n = col - C_;
    const float4* wk = (const float4*)(kn + n * C_);
    float t0 = 0, t1 = 0;
    for (int c = 0; c < 32; ++c) {
      float4 a0 = g0[c], a1 = g1[c], vk = wk[c];
      t0 += a0.x * vk.x + a0.y * vk.y + a0.z * vk.z + a0.w * vk.w;
      t1 += a1.x * vk.x + a1.y * vk.y + a1.z * vk.z + a1.w * vk.w;
    }
    float k0v = kn[n * C_ + lane], k1v = kn[n * C_ + 64 + lane];
    float dN = wredsum(k0v * t0 + k1v * t1);
    float kx = wredsum(k0v * sx0 + k1v * sx1);
    if (lane == 0) { diagN[b * N_ + n] = dN; ksx[b * N_ + n] = kx; }
  }
}

// ---------------- Kernel 3: per-batch assembly -> c1[b,c], c0[b,c] ----------
// Outputs folded epilogue coefficients: c1 = sigma*A, c0 = sigma*(A*bo - B)
__global__ __launch_bounds__(128) void k_asm(
    const float* diagR, const float* diagSA, const float* colsumSA, const float* diagO,
    const float* prv, const float* psav, const float* pov,
    const float* rel, const float* diagN, const float* ksx,
    const float* br, const float* bo, const float* bsa, const float* alpha,
    const float* sigma, float* C1out, float* C0out) {
  const int b = blockIdx.x;
  const int t = threadIdx.x;
  __shared__ float rb2[2];
  __shared__ float att_s[C_][N_ + 1];
  __shared__ float s1_s[C_], s2_s[C_];
  __shared__ float inv_s[N_], fmi_s[N_];
  const float hw = (float)HW_;
  const float bsa_c = bsa[t], br_c = br[t], bo_c = bo[t];
  const float psa_c = psav[b * C_ + t], pr_c = prv[b * C_ + t], po_c = pov[b * C_ + t];

  float bsum, psum, mx, ssum;
  { float wv = wredsum(bsa_c); if ((t & 63) == 0) rb2[t >> 6] = wv; __syncthreads();
    bsum = rb2[0] + rb2[1]; __syncthreads(); }
  { float wv = wredsum(psa_c); if ((t & 63) == 0) rb2[t >> 6] = wv; __syncthreads();
    psum = rb2[0] + rb2[1]; __syncthreads(); }

  const float nxr = sqrtf(fmaxf(diagR[b * C_ + t] + 2.f * br_c * pr_c + hw * br_c * br_c, 0.f));
  s1_s[t] = po_c + hw * bo_c;
  s2_s[t] = diagO[b * C_ + t] + 2.f * bo_c * po_c + hw * bo_c * bo_c;
  const float colsum = colsumSA[b * C_ + t] + bsum * psa_c + bsa_c * (psum + hw * bsum);
  const float diagv = diagSA[b * C_ + t] + 2.f * bsa_c * psa_c + hw * bsa_c * bsa_c;
  const float fm = (colsum - diagv) * (1.f / (float)C_);

  { float wv = wredmax(fm); if ((t & 63) == 0) rb2[t >> 6] = wv; __syncthreads();
    mx = fmaxf(rb2[0], rb2[1]); __syncthreads(); }
  const float ee = expf(fm - mx);
  { float wv = wredsum(ee); if ((t & 63) == 0) rb2[t >> 6] = wv; __syncthreads();
    ssum = rb2[0] + rb2[1]; __syncthreads(); }
  const float reg = ee / ssum;

  float r[N_];
  float rmax = -1e30f;
#pragma unroll
  for (int n = 0; n < N_; ++n) {
    float al = fminf(fmaxf(alpha[n], 0.f), 1.f);
    float nxn = sqrtf(fmaxf(diagN[b * N_ + n], 0.f));
    float rv = (rel[(b * N_ + n) * C_ + t] + br_c * ksx[b * N_ + n]) / (nxn * nxr + EPS_) + al * reg;
    r[n] = rv; rmax = fmaxf(rmax, rv);
  }
  float es = 0.f;
#pragma unroll
  for (int n = 0; n < N_; ++n) { r[n] = expf(r[n] - rmax); es += r[n]; }
  const float ies = 1.f / es;
#pragma unroll
  for (int n = 0; n < N_; ++n) att_s[t][n] = r[n] * ies;
  __syncthreads();

  {
    const int nn = t >> 3, g = t & 7;     // 8 lanes per class n
    float sa = 0.f, sh = 0.f, sq = 0.f;
#pragma unroll 4
    for (int c = g; c < C_; c += 8) {
      float a = att_s[c][nn];
      sa += a; sh += a * s1_s[c]; sq += a * a * s2_s[c];
    }
#pragma unroll
    for (int o = 4; o > 0; o >>= 1) {
      sa += __shfl_xor(sa, o, 64);
      sh += __shfl_xor(sh, o, 64);
      sq += __shfl_xor(sq, o, 64);
    }
    if (g == 0) {
      float cnt = sa * hw + EPS_;
      float fmean = sh / cnt;
      float sqv = sq - 2.f * fmean * sh + fmean * fmean * ((float)C_ * hw);
      float fstd = sqrtf(fmaxf(sqv, 0.f) / cnt);
      float inv = 1.f / (fstd + EPS_);
      inv_s[nn] = inv; fmi_s[nn] = fmean * inv;
    }
  }
  __syncthreads();

  float Ac = 0.f, Bc = 0.f;
#pragma unroll
  for (int n = 0; n < N_; ++n) { float a = att_s[t][n]; Ac += a * inv_s[n]; Bc += a * fmi_s[n]; }
  const float sg = sigma[0];
  C1out[b * C_ + t] = sg * Ac;
  C0out[b * C_ + t] = sg * (Ac * bo_c - Bc);
}

// ---------------- Kernel 4: out = x + c1[c]*(Wo x)[c,p] + c0[c] -------------
// Round-2 design (kept): single 128-px tile per block; swizzle
// f(row)=(row^(row>>2))&7 on byte bits 4-6 (bijective for both write rows
// 4l+pp and read rows 16p2+n); x kept in registers; acc routed through a
// 64 KB fp32 LDS buffer back to staging layout -> no second x fetch and
// fully-coalesced float4 stores. 2 blocks/CU at LB(512,4).
__global__ __launch_bounds__(512, 4) void k_out(
    const float* __restrict__ x, const u16* __restrict__ wo_bf,
    const float* __restrict__ c1g, const float* __restrict__ c0g,
    float* __restrict__ out) {
  __shared__ f4v smem4[4096];      // 65536 B union: bf16 X^T tile, then fp32 acc
  char* lds = (char*)smem4;
  const int b = blockIdx.y;
  const int tid = threadIdx.x, lane = tid & 63, w = tid >> 6;  // wave 0..7
  const int n = lane & 15, q = lane >> 4;
  const int co = tid >> 5;           // ch-octet 0..15 (ch 8co..8co+7)
  const int l  = tid & 31;           // px-quad  0..31 (px 4l..4l+3)
  const int p0 = blockIdx.x * 128;

  // per-wave Wo fragments: af[s] = Wo_bf16[16w+n][32s+8q .. +7]
  s8v af[4];
#pragma unroll
  for (int s = 0; s < 4; ++s)
    af[s] = *(const s8v*)(wo_bf + (16 * w + n) * C_ + 32 * s + 8 * q);

  // epilogue coefficients for this thread's 8 channels
  float c1[8], c0[8];
#pragma unroll
  for (int r = 0; r < 8; ++r) {
    c1[r] = c1g[b * C_ + 8 * co + r];
    c0[r] = c0g[b * C_ + 8 * co + r];
  }

  const float* xb = x + (size_t)b * C_ * HW_;
  float* ob = out + (size_t)b * C_ * HW_;

  // load x: 8 ch x 4 px per thread, 512-B contiguous segments per half-wave
  float4 v[8];
  const float* src = xb + (size_t)(8 * co) * HW_ + p0 + 4 * l;
#pragma unroll
  for (int r = 0; r < 8; ++r) v[r] = *(const float4*)(src + (size_t)r * HW_);

  // stage transposed bf16 tile: row = px-local (256 B of ch), swizzled
  {
    const float* vf = (const float*)v;
#pragma unroll
    for (int pp = 0; pp < 4; ++pp) {
      const int row = 4 * l + pp;
      s8v s;
#pragma unroll
      for (int r = 0; r < 8; ++r) s[r] = (short)f2b(vf[4 * r + pp]);
      *(s8v*)(lds + row * 256 + ((16 * co) ^ (((row ^ (row >> 2)) & 7) << 4))) = s;
    }
  }
  __syncthreads();

  // MFMA: wave w -> o-rows 16w..16w+15, all 128 px
  f4v acc[8];
#pragma unroll
  for (int p2 = 0; p2 < 8; ++p2) acc[p2] = (f4v){0.f, 0.f, 0.f, 0.f};
#pragma unroll
  for (int s = 0; s < 4; ++s) {
#pragma unroll
    for (int p2 = 0; p2 < 8; ++p2) {
      const int row = 16 * p2 + n;
      s8v bfr = *(const s8v*)(lds + row * 256 +
                              ((64 * s + 16 * q) ^ (((row ^ (row >> 2)) & 7) << 4)));
      acc[p2] = __builtin_amdgcn_mfma_f32_16x16x32_bf16(af[s], bfr, acc[p2], 0, 0, 0);
    }
  }
  __syncthreads();   // bf16 tile dead; reuse smem as fp32 acc buffer

  // acc -> LDS fp32 [px][o] (512 B/row), swizzled; quad o = 16w+4q .. +3
#pragma unroll
  for (int p2 = 0; p2 < 8; ++p2) {
    const int px = 16 * p2 + n;
    *(f4v*)(lds + px * 512 + ((64 * w + 16 * q) ^ (((px ^ (px >> 2)) & 7) << 4))) = acc[p2];
  }
  __syncthreads();

  // readback in staging layout + epilogue + coalesced float4 stores
  f4v ra[4], rb_[4];   // ra[pp] = acc ch 8co..+3 at px 4l+pp; rb_ = ch 8co+4..+7
#pragma unroll
  for (int pp = 0; pp < 4; ++pp) {
    const int px = 4 * l + pp;
    const int g = ((px ^ (px >> 2)) & 7) << 4;
    ra[pp]  = *(const f4v*)(lds + px * 512 + ((32 * co) ^ g));
    rb_[pp] = *(const f4v*)(lds + px * 512 + ((32 * co + 16) ^ g));
  }
  float* obp = ob + (size_t)(8 * co) * HW_ + p0 + 4 * l;
#pragma unroll
  for (int r = 0; r < 4; ++r) {
    float4 o4;
    o4.x = v[r].x + c1[r] * ra[0][r] + c0[r];
    o4.y = v[r].y + c1[r] * ra[1][r] + c0[r];
    o4.z = v[r].z + c1[r] * ra[2][r] + c0[r];
    o4.w = v[r].w + c1[r] * ra[3][r] + c0[r];
    *(float4*)(obp + (size_t)r * HW_) = o4;
  }
#pragma unroll
  for (int r = 0; r < 4; ++r) {
    float4 o4;
    o4.x = v[4 + r].x + c1[4 + r] * rb_[0][r] + c0[4 + r];
    o4.y = v[4 + r].y + c1[4 + r] * rb_[1][r] + c0[4 + r];
    o4.z = v[4 + r].z + c1[4 + r] * rb_[2][r] + c0[4 + r];
    o4.w = v[4 + r].w + c1[4 + r] * rb_[3][r] + c0[4 + r];
    *(float4*)(obp + (size_t)(4 + r) * HW_) = o4;
  }
}

extern "C" void kernel_launch(void* const* d_in, const int* in_sizes, int n_in,
                              void* d_out, int out_size, void* d_ws, size_t ws_size,
                              hipStream_t stream) {
  (void)in_sizes; (void)n_in; (void)out_size; (void)ws_size;
  const float* x     = (const float*)d_in[0];
  const float* Wsa   = (const float*)d_in[1];
  const float* bsa   = (const float*)d_in[2];
  const float* Wr    = (const float*)d_in[3];
  const float* br    = (const float*)d_in[4];
  const float* kn    = (const float*)d_in[5];
  const float* Wo    = (const float*)d_in[6];
  const float* bo    = (const float*)d_in[7];
  const float* alpha = (const float*)d_in[8];
  const float* sigma = (const float*)d_in[9];
  float* out = (float*)d_out;
  float* ws  = (float*)d_ws;

  float* G        = ws;            // 131072
  float* sx       = ws + 131072;   // 1024
  float* diagR    = ws + 132096;   // 1024
  float* diagSA   = ws + 133120;   // 1024
  float* colsumSA = ws + 134144;   // 1024
  float* diagO    = ws + 135168;   // 1024
  float* prv      = ws + 136192;   // 1024
  float* psav     = ws + 137216;   // 1024
  float* pov      = ws + 138240;   // 1024
  float* rel      = ws + 139264;   // 16384
  float* diagN    = ws + 155648;   // 128
  float* ksx      = ws + 155776;   // 128
  float* u        = ws + 155904;   // 128
  float* C1w      = ws + 156032;   // 1024
  float* C0w      = ws + 157056;   // 1024
  u16*   wo_bf    = (u16*)(ws + 158080);  // 16384 u16 = 8192 floats

  // d_out doubles as scratch for Gram partials until k_out overwrites it:
  float* pbuf = out;               // 64*8*16384 = 8388608 floats
  float* psx  = out + 8388608;     // 64*8*128   = 65536 floats

  k_gram<<<dim3(65, 8), 512, 0, stream>>>(x, pbuf, psx, Wsa, kn, Wo, u,
      out + (size_t)B_ * C_ * HW_, wo_bf);
  k_greduce<<<264, 128, 0, stream>>>((const float4*)pbuf, psx, G, sx);
  k_cols<<<dim3(144, 8), 64, 0, stream>>>(G, sx, Wr, Wsa, Wo, kn, u,
      diagR, diagSA, colsumSA, diagO, prv, psav, pov, rel, diagN, ksx);
  k_asm<<<8, 128, 0, stream>>>(diagR, diagSA, colsumSA, diagO, prv, psav, pov,
      rel, diagN, ksx, br, bo, bsa, alpha, sigma, C1w, C0w);
  k_out<<<dim3(128, 8), 512, 0, stream>>>(x, wo_bf, C1w, C0w, out);
}